// Round 8
// baseline (185.324 us; speedup 1.0000x reference)
//
#include <hip/hip_runtime.h>

#define NN 4096
#define DIM 128
#define TN 32            // q-rows per block
#define TM 128           // m-tile size
#define NTILES 16        // tiles per block (half of the 32 global tiles)

typedef __attribute__((ext_vector_type(8))) short bf16x8;
typedef __attribute__((ext_vector_type(4))) float f32x4;

#define LSTRIDE 136                    // ushorts per row (272 B, 16B-aligned)
#define REGION  (128 * LSTRIDE)        // one layout region (34816 ushorts)
#define TILE_USH (2 * REGION)          // Hrow|Hcol per tile = 69632 B
#define PST 136                        // P row stride (ushorts)

__device__ inline unsigned short f2bf(float x) {
    union { float f; unsigned u; } v; v.f = x;
    unsigned r = v.u + 0x7FFFu + ((v.u >> 16) & 1u);
    return (unsigned short)(r >> 16);
}

// ---- prep A: hidden fp32 -> Hpack[32 tiles][Hrow region | Hcol region] ----
__global__ __launch_bounds__(256) void prep_pack_kernel(
    const float* __restrict__ hidden,
    unsigned short* __restrict__ Hpack)
{
    __shared__ unsigned short T[128 * LSTRIDE];
    const int tid = threadIdx.x;
    const int t0  = blockIdx.x;
    const int m0  = t0 * TM;
    unsigned short* rowdst = Hpack + (size_t)t0 * TILE_USH;
    unsigned short* coldst = rowdst + REGION;

    #pragma unroll
    for (int it = 0; it < 16; ++it) {
        int idx = tid + 256 * it;
        int row = idx >> 5;
        int c4  = (idx & 31) * 4;
        float4 v = *(const float4*)(hidden + (size_t)(m0 + row) * DIM + c4);
        ushort4 o;
        o.x = f2bf(v.x); o.y = f2bf(v.y); o.z = f2bf(v.z); o.w = f2bf(v.w);
        *(ushort4*)(rowdst + row * LSTRIDE + c4) = o;
        T[(c4 + 0) * LSTRIDE + row] = o.x;
        T[(c4 + 1) * LSTRIDE + row] = o.y;
        T[(c4 + 2) * LSTRIDE + row] = o.z;
        T[(c4 + 3) * LSTRIDE + row] = o.w;
    }
    __syncthreads();
    #pragma unroll
    for (int it = 0; it < 8; ++it) {
        int idx = tid + 256 * it;
        int d  = idx >> 4;
        int c8 = (idx & 15) * 8;
        uint4 v = *(const uint4*)(T + d * LSTRIDE + c8);
        *(uint4*)(coldst + d * LSTRIDE + c8) = v;
    }
}

// ---- prep B: adj int32 -> transposed u8 chunks adjp[nb][gt][m 128][r 32] ----
__global__ __launch_bounds__(256) void prep_adj_kernel(
    const int* __restrict__ adj, unsigned char* __restrict__ adjp)
{
    const int p   = blockIdx.x;        // 0..4095 = nb*32 + gt
    const int nb  = p >> 5, gt = p & 31;
    const int tid = threadIdx.x;
    const int m   = tid >> 1;
    const int rh  = (tid & 1) * 16;
    unsigned char bytes[16];
    #pragma unroll
    for (int rr = 0; rr < 16; ++rr)
        bytes[rr] = (unsigned char)adj[(size_t)(nb * 32 + rh + rr) * NN + gt * 128 + m];
    *(uint4*)(adjp + (size_t)p * 4096 + m * 32 + rh) = *(const uint4*)bytes;
}

// ---- main: TN=32, double-buffered LDS pipeline, raw lgkm-only mid barrier ----
__global__ __launch_bounds__(512, 2) void gat_flash_kernel(
    const float* __restrict__ hidden,        // fp32 (Q only)
    const unsigned short* __restrict__ Hpack,
    const unsigned char* __restrict__ adjp,
    const float* __restrict__ W,
    const float* __restrict__ bvec,
    float*       __restrict__ Opart,         // [256][TN][DIM]
    float*       __restrict__ lpart)         // [256][TN]
{
    __shared__ __align__(16) unsigned short HH[2][TILE_USH];   // 139264 B
    __shared__ __align__(16) unsigned short Plc[TN * PST];     // 8704 B
    __shared__ float redsum[8][16];

    const int tid  = threadIdx.x;
    const int w    = tid >> 6;
    const int lane = tid & 63;
    const int g    = lane >> 4;
    const int l15  = lane & 15;
    const int blk  = blockIdx.x;
    const int nb   = blk >> 1;         // 0..127 row-group of 32
    const int half = blk & 1;
    const int n0   = nb * TN;
    const int gt0  = half * NTILES;
    const int rg   = w >> 2;           // 0/1: which 16-row group
    const int ms   = w & 3;            // QK m-slice (32 wide) / PV d-quarter
    const float NEG = -9.0e15f;

    const float b0 = bvec[0], b1 = bvec[1], b2 = bvec[2], b3 = bvec[3];

    // ---- prologue: issue tile-0 staging loads into regs ----
    uint4 st[9];
    {
        const uint4* src = (const uint4*)(Hpack + (size_t)gt0 * TILE_USH);
        #pragma unroll
        for (int it = 0; it < 8; ++it) st[it] = src[tid + 512 * it];
        if (tid < 256) st[8] = src[4096 + tid];
    }
    // Q into HH[1] rows k*32+r (overlaps the staging loads)
    {
        int qr = tid >> 2;             // 0..127 = k*32 + r
        int r  = qr & 31;
        int d0 = (tid & 3) * 32;
        const float* hrow = hidden + (size_t)(n0 + r) * DIM + d0;
        const float* wrow = W + (qr >> 5) * DIM + d0;
        unsigned short* qdst = &HH[1][qr * LSTRIDE + d0];
        #pragma unroll
        for (int c = 0; c < 8; ++c) {
            float4 hv = *(const float4*)(hrow + 4 * c);
            float4 wv = *(const float4*)(wrow + 4 * c);
            ushort4 o;
            o.x = f2bf(hv.x * wv.x); o.y = f2bf(hv.y * wv.y);
            o.z = f2bf(hv.z * wv.z); o.w = f2bf(hv.w * wv.w);
            *(ushort4*)(qdst + 4 * c) = o;
        }
    }
    // tile-0 regs -> HH[0]
    {
        uint4* dst = (uint4*)&HH[0][0];
        #pragma unroll
        for (int it = 0; it < 8; ++it) dst[tid + 512 * it] = st[it];
        if (tid < 256) dst[4096 + tid] = st[8];
    }
    __syncthreads();

    // A-fragments for this wave's 16 rows (persist in regs; HH[1] is reused
    // as a staging buffer starting end of tile 0 -- safe: Af reads drain at
    // the tile-0 lgkm barrier before any wave writes HH[1])
    bf16x8 Af[4][4];
    #pragma unroll
    for (int k = 0; k < 4; ++k)
        #pragma unroll
        for (int ks = 0; ks < 4; ++ks)
            Af[k][ks] = *(const bf16x8*)&HH[1][(k * 32 + rg * 16 + l15) * LSTRIDE + ks * 32 + 8 * g];

    float lrow[4] = {0.f, 0.f, 0.f, 0.f};
    f32x4 Oacc[2];
    Oacc[0] = (f32x4){0.f, 0.f, 0.f, 0.f};
    Oacc[1] = (f32x4){0.f, 0.f, 0.f, 0.f};

    const unsigned char* apb = adjp + (size_t)(nb * 32 + gt0) * 4096;
    uchar4 av4[2], avn4[2];
    av4[0] = *(const uchar4*)&apb[(ms * 32 + l15) * 32 + rg * 16 + 4 * g];
    av4[1] = *(const uchar4*)&apb[(ms * 32 + 16 + l15) * 32 + rg * 16 + 4 * g];

    for (int tile = 0; tile < NTILES; ++tile) {
        const int cur = tile & 1;
        const int nxt = cur ^ 1;

        // ---- issue next-tile staging loads (stay in flight across compute) ----
        if (tile + 1 < NTILES) {
            const uint4* src = (const uint4*)(Hpack + (size_t)(gt0 + tile + 1) * TILE_USH);
            #pragma unroll
            for (int it = 0; it < 8; ++it) st[it] = src[tid + 512 * it];
            if (tid < 256) st[8] = src[4096 + tid];
            const unsigned char* apn = apb + (size_t)(tile + 1) * 4096;
            avn4[0] = *(const uchar4*)&apn[(ms * 32 + l15) * 32 + rg * 16 + 4 * g];
            avn4[1] = *(const uchar4*)&apn[(ms * 32 + 16 + l15) * 32 + rg * 16 + 4 * g];
        }

        // ---- QK: S[k][ch] over m-slice [ms*32, +32) for rows rg*16..+16 ----
        f32x4 S[4][2];
        #pragma unroll
        for (int k = 0; k < 4; ++k) {
            S[k][0] = (f32x4){0.f, 0.f, 0.f, 0.f};
            S[k][1] = (f32x4){0.f, 0.f, 0.f, 0.f};
        }
        #pragma unroll
        for (int ks = 0; ks < 4; ++ks) {
            #pragma unroll
            for (int ch = 0; ch < 2; ++ch) {
                bf16x8 B = *(const bf16x8*)&HH[cur][(ms * 32 + ch * 16 + l15) * LSTRIDE + ks * 32 + 8 * g];
                #pragma unroll
                for (int k = 0; k < 4; ++k)
                    S[k][ch] = __builtin_amdgcn_mfma_f32_16x16x32_bf16(Af[k][ks], B, S[k][ch], 0, 0, 0);
            }
        }

        // ---- select + leakyrelu + exp (no-max softmax; scores bounded) ----
        #pragma unroll
        for (int ch = 0; ch < 2; ++ch) {
            const unsigned char* ab = (const unsigned char*)&av4[ch];
            #pragma unroll
            for (int t = 0; t < 4; ++t) {
                int a = ab[t];
                float s = S[0][ch][t] + b0;
                s = (a == 2) ? S[1][ch][t] + b1 : s;
                s = (a == 3) ? S[2][ch][t] + b2 : s;
                s = (a == 4) ? S[3][ch][t] + b3 : s;
                float e = fmaxf(s, 0.2f * s);
                e = (a == 0) ? NEG : e;
                float p = __expf(e);           // exp(-9e15) -> exactly 0
                lrow[t] += p;
                Plc[(rg * 16 + 4 * g + t) * PST + ms * 32 + ch * 16 + l15] = f2bf(p);
            }
        }

        // ---- P-ready barrier: LDS-only drain, staging loads stay in flight ----
        asm volatile("s_waitcnt lgkmcnt(0)\n\ts_barrier" ::: "memory");

        // ---- PV: rows rg*16..+16, d-quarter [ms*32, +32), K=128 ----
        #pragma unroll
        for (int c4 = 0; c4 < 4; ++c4) {
            bf16x8 Pa = *(const bf16x8*)&Plc[(rg * 16 + l15) * PST + c4 * 32 + 8 * g];
            #pragma unroll
            for (int dt = 0; dt < 2; ++dt) {
                bf16x8 Bv = *(const bf16x8*)&HH[cur][REGION + (ms * 32 + dt * 16 + l15) * LSTRIDE + c4 * 32 + 8 * g];
                Oacc[dt] = __builtin_amdgcn_mfma_f32_16x16x32_bf16(Pa, Bv, Oacc[dt], 0, 0, 0);
            }
        }

        // ---- staged regs -> other buffer ----
        if (tile + 1 < NTILES) {
            uint4* dst = (uint4*)&HH[nxt][0];
            #pragma unroll
            for (int it = 0; it < 8; ++it) dst[tid + 512 * it] = st[it];
            if (tid < 256) dst[4096 + tid] = st[8];
            av4[0] = avn4[0]; av4[1] = avn4[1];
        }
        __syncthreads();   // drains staging stores; buffer swap
    }

    // ---- epilogue ----
    #pragma unroll
    for (int t = 0; t < 4; ++t) {
        float v = lrow[t];
        v += __shfl_xor(v, 1); v += __shfl_xor(v, 2);
        v += __shfl_xor(v, 4); v += __shfl_xor(v, 8);
        if (l15 == 0) redsum[w][4 * g + t] = v;
    }
    __syncthreads();
    if (tid < 32) {
        int rgp = tid >> 4, rr = tid & 15;
        float s = redsum[rgp * 4 + 0][rr] + redsum[rgp * 4 + 1][rr]
                + redsum[rgp * 4 + 2][rr] + redsum[rgp * 4 + 3][rr];
        lpart[blk * 32 + tid] = s;
    }
    float* Ob = Opart + (size_t)blk * TN * DIM;
    #pragma unroll
    for (int dt = 0; dt < 2; ++dt)
        #pragma unroll
        for (int t = 0; t < 4; ++t)
            Ob[(rg * 16 + 4 * g + t) * DIM + ms * 32 + dt * 16 + l15] = Oacc[dt][t];
}

// ---- combine the two m-halves ----
__global__ __launch_bounds__(256) void combine_kernel(
    const float* __restrict__ Opart, const float* __restrict__ lpart,
    float* __restrict__ out)
{
    int idx = blockIdx.x * 256 + threadIdx.x;
    int r = idx >> 7, d = idx & 127;
    int nb = r >> 5, rr = r & 31;
    float O0 = Opart[(size_t)(nb * 2) * (TN * DIM) + rr * 128 + d];
    float O1 = Opart[(size_t)(nb * 2 + 1) * (TN * DIM) + rr * 128 + d];
    float l0 = lpart[(nb * 2) * 32 + rr];
    float l1 = lpart[(nb * 2 + 1) * 32 + rr];
    out[idx] = (O0 + O1) / (l0 + l1);
}

extern "C" void kernel_launch(void* const* d_in, const int* in_sizes, int n_in,
                              void* d_out, int out_size, void* d_ws, size_t ws_size,
                              hipStream_t stream) {
    const float* hidden = (const float*)d_in[0];
    const int*   adj    = (const int*)d_in[1];
    const float* W      = (const float*)d_in[2];
    const float* b      = (const float*)d_in[3];
    float* out = (float*)d_out;

    char* ws = (char*)d_ws;
    unsigned short* Hpack = (unsigned short*)ws;                 // 2.18 MB
    unsigned char*  adjp  = (unsigned char*)(ws + (4u << 20));   // 16 MB
    float* Opart = (float*)(ws + (20u << 20));                   // 4 MB
    float* lpart = (float*)(ws + (24u << 20));                   // 32 KB

    prep_pack_kernel<<<NN / TM, 256, 0, stream>>>(hidden, Hpack);
    prep_adj_kernel<<<128 * 32, 256, 0, stream>>>(adj, adjp);
    gat_flash_kernel<<<256, 512, 0, stream>>>(hidden, Hpack, adjp, W, b, Opart, lpart);
    combine_kernel<<<NN * DIM / 256, 256, 0, stream>>>(Opart, lpart, out);
}

// Round 9
// 152.532 us; speedup vs baseline: 1.2150x; 1.2150x over previous
//
#include <hip/hip_runtime.h>

#define NN 4096
#define DIM 128
#define TN 32            // q-rows per block
#define TM 128           // m-tile size
#define NTILES 16        // tiles per block (half of the 32 global tiles)

typedef __attribute__((ext_vector_type(8))) short bf16x8;
typedef __attribute__((ext_vector_type(4))) float f32x4;

#define LSTRIDE 136                    // ushorts per row (272 B, 16B-aligned)
#define REGION  (128 * LSTRIDE)        // one layout region (34816 ushorts)
#define TILE_USH (2 * REGION)          // Hrow|Hcol per tile = 69632 B
#define TILE_CHUNKS 68                 // 69632 / 1024
#define PST 136                        // P row stride (ushorts)

__device__ inline unsigned short f2bf(float x) {
    union { float f; unsigned u; } v; v.f = x;
    unsigned r = v.u + 0x7FFFu + ((v.u >> 16) & 1u);
    return (unsigned short)(r >> 16);
}

// async global->LDS DMA, 16 B/lane, dest = wave-uniform base + lane*16
__device__ inline void dma16(const void* g, void* l) {
    __builtin_amdgcn_global_load_lds(
        (const __attribute__((address_space(1))) void*)g,
        (__attribute__((address_space(3))) void*)l,
        16, 0, 0);
}

// ---- prep A: hidden fp32 -> Hpack[32 tiles][Hrow region | Hcol region] ----
__global__ __launch_bounds__(256) void prep_pack_kernel(
    const float* __restrict__ hidden,
    unsigned short* __restrict__ Hpack)
{
    __shared__ unsigned short T[128 * LSTRIDE];
    const int tid = threadIdx.x;
    const int t0  = blockIdx.x;
    const int m0  = t0 * TM;
    unsigned short* rowdst = Hpack + (size_t)t0 * TILE_USH;
    unsigned short* coldst = rowdst + REGION;

    #pragma unroll
    for (int it = 0; it < 16; ++it) {
        int idx = tid + 256 * it;
        int row = idx >> 5;
        int c4  = (idx & 31) * 4;
        float4 v = *(const float4*)(hidden + (size_t)(m0 + row) * DIM + c4);
        ushort4 o;
        o.x = f2bf(v.x); o.y = f2bf(v.y); o.z = f2bf(v.z); o.w = f2bf(v.w);
        *(ushort4*)(rowdst + row * LSTRIDE + c4) = o;
        T[(c4 + 0) * LSTRIDE + row] = o.x;
        T[(c4 + 1) * LSTRIDE + row] = o.y;
        T[(c4 + 2) * LSTRIDE + row] = o.z;
        T[(c4 + 3) * LSTRIDE + row] = o.w;
    }
    __syncthreads();
    #pragma unroll
    for (int it = 0; it < 8; ++it) {
        int idx = tid + 256 * it;
        int d  = idx >> 4;
        int c8 = (idx & 15) * 8;
        uint4 v = *(const uint4*)(T + d * LSTRIDE + c8);
        *(uint4*)(coldst + d * LSTRIDE + c8) = v;
    }
}

// ---- prep B: adj int32 -> transposed u8 chunks adjp[nb][gt][m 128][r 32] ----
__global__ __launch_bounds__(256) void prep_adj_kernel(
    const int* __restrict__ adj, unsigned char* __restrict__ adjp)
{
    const int p   = blockIdx.x;        // 0..4095 = nb*32 + gt
    const int nb  = p >> 5, gt = p & 31;
    const int tid = threadIdx.x;
    const int m   = tid >> 1;
    const int rh  = (tid & 1) * 16;
    unsigned char bytes[16];
    #pragma unroll
    for (int rr = 0; rr < 16; ++rr)
        bytes[rr] = (unsigned char)adj[(size_t)(nb * 32 + rh + rr) * NN + gt * 128 + m];
    *(uint4*)(adjp + (size_t)p * 4096 + m * 32 + rh) = *(const uint4*)bytes;
}

// ---- main: TN=32, double-buffered DMA pipeline (global_load_lds),
//      lgkm-only mid barrier; end-of-tile syncthreads drains the DMA ----
__global__ __launch_bounds__(512, 2) void gat_flash_kernel(
    const float* __restrict__ hidden,        // fp32 (Q only)
    const unsigned short* __restrict__ Hpack,
    const unsigned char* __restrict__ adjp,
    const float* __restrict__ W,
    const float* __restrict__ bvec,
    float*       __restrict__ Opart,         // [256][TN][DIM]
    float*       __restrict__ lpart)         // [256][TN]
{
    __shared__ __align__(16) unsigned short HH[2][TILE_USH];   // 139264 B
    __shared__ __align__(16) unsigned short Plc[TN * PST];     // 8704 B
    __shared__ float redsum[8][16];

    const int tid  = threadIdx.x;
    const int w    = tid >> 6;
    const int lane = tid & 63;
    const int g    = lane >> 4;
    const int l15  = lane & 15;
    const int blk  = blockIdx.x;
    const int nb   = blk >> 1;         // 0..127 row-group of 32
    const int half = blk & 1;
    const int n0   = nb * TN;
    const int gt0  = half * NTILES;
    const int rg   = w >> 2;           // 0/1: which 16-row group
    const int ms   = w & 3;            // QK m-slice (32 wide) / PV d-quarter
    const int lofs = lane * 16;
    const float NEG = -9.0e15f;

    const float b0 = bvec[0], b1 = bvec[1], b2 = bvec[2], b3 = bvec[3];

    // ---- prologue: DMA tile 0 -> HH[0] (overlaps Q compute below) ----
    {
        const char* src = (const char*)(Hpack + (size_t)gt0 * TILE_USH);
        char* dst = (char*)&HH[0][0];
        #pragma unroll
        for (int it = 0; it < 9; ++it) {
            int chunk = it * 8 + w;
            if (chunk < TILE_CHUNKS)
                dma16(src + chunk * 1024 + lofs, dst + chunk * 1024);
        }
    }
    // Q into HH[1] rows k*32+r
    {
        int qr = tid >> 2;             // 0..127 = k*32 + r
        int r  = qr & 31;
        int d0 = (tid & 3) * 32;
        const float* hrow = hidden + (size_t)(n0 + r) * DIM + d0;
        const float* wrow = W + (qr >> 5) * DIM + d0;
        unsigned short* qdst = &HH[1][qr * LSTRIDE + d0];
        #pragma unroll
        for (int c = 0; c < 8; ++c) {
            float4 hv = *(const float4*)(hrow + 4 * c);
            float4 wv = *(const float4*)(wrow + 4 * c);
            ushort4 o;
            o.x = f2bf(hv.x * wv.x); o.y = f2bf(hv.y * wv.y);
            o.z = f2bf(hv.z * wv.z); o.w = f2bf(hv.w * wv.w);
            *(ushort4*)(qdst + 4 * c) = o;
        }
    }
    __syncthreads();   // drains tile-0 DMA (vmcnt) + Q LDS writes (lgkm)

    // A-fragments for this wave's 16 rows; HH[1] becomes a staging buffer
    // after the next barrier
    bf16x8 Af[4][4];
    #pragma unroll
    for (int k = 0; k < 4; ++k)
        #pragma unroll
        for (int ks = 0; ks < 4; ++ks)
            Af[k][ks] = *(const bf16x8*)&HH[1][(k * 32 + rg * 16 + l15) * LSTRIDE + ks * 32 + 8 * g];
    __syncthreads();   // Af reads drained before tile-1 DMA may write HH[1]

    float lrow[4] = {0.f, 0.f, 0.f, 0.f};
    f32x4 Oacc[2];
    Oacc[0] = (f32x4){0.f, 0.f, 0.f, 0.f};
    Oacc[1] = (f32x4){0.f, 0.f, 0.f, 0.f};

    const unsigned char* apb = adjp + (size_t)(nb * 32 + gt0) * 4096;
    uchar4 av4[2], avn4[2];
    av4[0] = *(const uchar4*)&apb[(ms * 32 + l15) * 32 + rg * 16 + 4 * g];
    av4[1] = *(const uchar4*)&apb[(ms * 32 + 16 + l15) * 32 + rg * 16 + 4 * g];

    for (int tile = 0; tile < NTILES; ++tile) {
        const int cur = tile & 1;
        const int nxt = cur ^ 1;

        // ---- issue next-tile DMA into HH[nxt]; stays in flight all tile ----
        if (tile + 1 < NTILES) {
            const char* src = (const char*)(Hpack + (size_t)(gt0 + tile + 1) * TILE_USH);
            char* dst = (char*)&HH[nxt][0];
            #pragma unroll
            for (int it = 0; it < 9; ++it) {
                int chunk = it * 8 + w;
                if (chunk < TILE_CHUNKS)
                    dma16(src + chunk * 1024 + lofs, dst + chunk * 1024);
            }
            const unsigned char* apn = apb + (size_t)(tile + 1) * 4096;
            avn4[0] = *(const uchar4*)&apn[(ms * 32 + l15) * 32 + rg * 16 + 4 * g];
            avn4[1] = *(const uchar4*)&apn[(ms * 32 + 16 + l15) * 32 + rg * 16 + 4 * g];
        }

        // ---- QK: S[k][ch] over m-slice [ms*32, +32) for rows rg*16..+16 ----
        f32x4 S[4][2];
        #pragma unroll
        for (int k = 0; k < 4; ++k) {
            S[k][0] = (f32x4){0.f, 0.f, 0.f, 0.f};
            S[k][1] = (f32x4){0.f, 0.f, 0.f, 0.f};
        }
        #pragma unroll
        for (int ks = 0; ks < 4; ++ks) {
            #pragma unroll
            for (int ch = 0; ch < 2; ++ch) {
                bf16x8 B = *(const bf16x8*)&HH[cur][(ms * 32 + ch * 16 + l15) * LSTRIDE + ks * 32 + 8 * g];
                #pragma unroll
                for (int k = 0; k < 4; ++k)
                    S[k][ch] = __builtin_amdgcn_mfma_f32_16x16x32_bf16(Af[k][ks], B, S[k][ch], 0, 0, 0);
            }
        }

        // ---- select + leakyrelu + exp (no-max softmax; scores bounded) ----
        #pragma unroll
        for (int ch = 0; ch < 2; ++ch) {
            const unsigned char* ab = (const unsigned char*)&av4[ch];
            #pragma unroll
            for (int t = 0; t < 4; ++t) {
                int a = ab[t];
                float s = S[0][ch][t] + b0;
                s = (a == 2) ? S[1][ch][t] + b1 : s;
                s = (a == 3) ? S[2][ch][t] + b2 : s;
                s = (a == 4) ? S[3][ch][t] + b3 : s;
                float e = fmaxf(s, 0.2f * s);
                e = (a == 0) ? NEG : e;
                float p = __expf(e);           // exp(-9e15) -> exactly 0
                lrow[t] += p;
                Plc[(rg * 16 + 4 * g + t) * PST + ms * 32 + ch * 16 + l15] = f2bf(p);
            }
        }

        // ---- P-ready barrier: LDS-only drain; DMA stays in flight ----
        asm volatile("s_waitcnt lgkmcnt(0)\n\ts_barrier" ::: "memory");

        // ---- PV: rows rg*16..+16, d-quarter [ms*32, +32), K=128 ----
        #pragma unroll
        for (int c4 = 0; c4 < 4; ++c4) {
            bf16x8 Pa = *(const bf16x8*)&Plc[(rg * 16 + l15) * PST + c4 * 32 + 8 * g];
            #pragma unroll
            for (int dt = 0; dt < 2; ++dt) {
                bf16x8 Bv = *(const bf16x8*)&HH[cur][REGION + (ms * 32 + dt * 16 + l15) * LSTRIDE + c4 * 32 + 8 * g];
                Oacc[dt] = __builtin_amdgcn_mfma_f32_16x16x32_bf16(Pa, Bv, Oacc[dt], 0, 0, 0);
            }
        }

        av4[0] = avn4[0]; av4[1] = avn4[1];
        __syncthreads();   // vmcnt(0) drain == "HH[nxt] staged"; buffer swap
    }

    // ---- epilogue ----
    #pragma unroll
    for (int t = 0; t < 4; ++t) {
        float v = lrow[t];
        v += __shfl_xor(v, 1); v += __shfl_xor(v, 2);
        v += __shfl_xor(v, 4); v += __shfl_xor(v, 8);
        if (l15 == 0) redsum[w][4 * g + t] = v;
    }
    __syncthreads();
    if (tid < 32) {
        int rgp = tid >> 4, rr = tid & 15;
        float s = redsum[rgp * 4 + 0][rr] + redsum[rgp * 4 + 1][rr]
                + redsum[rgp * 4 + 2][rr] + redsum[rgp * 4 + 3][rr];
        lpart[blk * 32 + tid] = s;
    }
    float* Ob = Opart + (size_t)blk * TN * DIM;
    #pragma unroll
    for (int dt = 0; dt < 2; ++dt)
        #pragma unroll
        for (int t = 0; t < 4; ++t)
            Ob[(rg * 16 + 4 * g + t) * DIM + ms * 32 + dt * 16 + l15] = Oacc[dt][t];
}

// ---- combine the two m-halves ----
__global__ __launch_bounds__(256) void combine_kernel(
    const float* __restrict__ Opart, const float* __restrict__ lpart,
    float* __restrict__ out)
{
    int idx = blockIdx.x * 256 + threadIdx.x;
    int r = idx >> 7, d = idx & 127;
    int nb = r >> 5, rr = r & 31;
    float O0 = Opart[(size_t)(nb * 2) * (TN * DIM) + rr * 128 + d];
    float O1 = Opart[(size_t)(nb * 2 + 1) * (TN * DIM) + rr * 128 + d];
    float l0 = lpart[(nb * 2) * 32 + rr];
    float l1 = lpart[(nb * 2 + 1) * 32 + rr];
    out[idx] = (O0 + O1) / (l0 + l1);
}

extern "C" void kernel_launch(void* const* d_in, const int* in_sizes, int n_in,
                              void* d_out, int out_size, void* d_ws, size_t ws_size,
                              hipStream_t stream) {
    const float* hidden = (const float*)d_in[0];
    const int*   adj    = (const int*)d_in[1];
    const float* W      = (const float*)d_in[2];
    const float* b      = (const float*)d_in[3];
    float* out = (float*)d_out;

    char* ws = (char*)d_ws;
    unsigned short* Hpack = (unsigned short*)ws;                 // 2.18 MB
    unsigned char*  adjp  = (unsigned char*)(ws + (4u << 20));   // 16 MB
    float* Opart = (float*)(ws + (20u << 20));                   // 4 MB
    float* lpart = (float*)(ws + (24u << 20));                   // 32 KB

    prep_pack_kernel<<<NN / TM, 256, 0, stream>>>(hidden, Hpack);
    prep_adj_kernel<<<128 * 32, 256, 0, stream>>>(adj, adjp);
    gat_flash_kernel<<<256, 512, 0, stream>>>(hidden, Hpack, adjp, W, b, Opart, lpart);
    combine_kernel<<<NN * DIM / 256, 256, 0, stream>>>(Opart, lpart, out);
}

// Round 10
// 149.457 us; speedup vs baseline: 1.2400x; 1.0206x over previous
//
#include <hip/hip_runtime.h>

#define NN 4096
#define DIM 128
#define TN 32            // q-rows per block
#define TM 64            // m-tile size
#define NTILES 16        // tiles per block (quarter of the 64 global tiles)
#define NSPLIT 4         // split-m factor

typedef __attribute__((ext_vector_type(8))) short bf16x8;
typedef __attribute__((ext_vector_type(4))) float f32x4;

#define LSTRIDE 136                    // Hrow: ushorts per row (272 B)
#define HCST    72                     // Hcol: ushorts per row (144 B)
#define HROW_USH (TM * LSTRIDE)        // 8704 ushorts
#define HCOL_USH (DIM * HCST)          // 9216 ushorts
#define TILE_USH (HROW_USH + HCOL_USH) // 17920 ushorts = 35840 B
#define TILE_CHUNKS 35                 // 35840 / 1024
#define PST 72                         // P row stride (ushorts, 144 B, 16B-aligned)

__device__ inline unsigned short f2bf(float x) {
    union { float f; unsigned u; } v; v.f = x;
    unsigned r = v.u + 0x7FFFu + ((v.u >> 16) & 1u);
    return (unsigned short)(r >> 16);
}

// async global->LDS DMA, 16 B/lane, dest = wave-uniform base + lane*16
__device__ inline void dma16(const void* g, void* l) {
    __builtin_amdgcn_global_load_lds(
        (const __attribute__((address_space(1))) void*)g,
        (__attribute__((address_space(3))) void*)l,
        16, 0, 0);
}

// ---- prep: hidden fp32 -> Hpack[64 tiles][Hrow 64x136 | Hcol 128x72] bf16 ----
__global__ __launch_bounds__(256) void prep_pack_kernel(
    const float* __restrict__ hidden,
    unsigned short* __restrict__ Hpack)
{
    __shared__ unsigned short T[DIM * HCST];   // [d][m-in-tile]
    const int tid = threadIdx.x;
    const int t0  = blockIdx.x;        // tile 0..63
    const int m0  = t0 * TM;
    unsigned short* rowdst = Hpack + (size_t)t0 * TILE_USH;
    unsigned short* coldst = rowdst + HROW_USH;

    #pragma unroll
    for (int it = 0; it < 8; ++it) {
        int idx = tid + 256 * it;      // 64 rows x 32 float4 chunks
        int row = idx >> 5;
        int c4  = (idx & 31) * 4;
        float4 v = *(const float4*)(hidden + (size_t)(m0 + row) * DIM + c4);
        ushort4 o;
        o.x = f2bf(v.x); o.y = f2bf(v.y); o.z = f2bf(v.z); o.w = f2bf(v.w);
        *(ushort4*)(rowdst + row * LSTRIDE + c4) = o;
        T[(c4 + 0) * HCST + row] = o.x;
        T[(c4 + 1) * HCST + row] = o.y;
        T[(c4 + 2) * HCST + row] = o.z;
        T[(c4 + 3) * HCST + row] = o.w;
    }
    __syncthreads();
    #pragma unroll
    for (int it = 0; it < 4; ++it) {
        int idx = tid + 256 * it;      // 128 d x 8 chunks of 8 ushorts
        int d  = idx >> 3;
        int c8 = (idx & 7) * 8;
        uint4 v = *(const uint4*)(T + d * HCST + c8);
        *(uint4*)(coldst + d * HCST + c8) = v;
    }
}

// ---- main: TM=64 double-buffered DMA pipeline, 2 blocks/CU, direct adj ----
__global__ __launch_bounds__(512, 4) void gat_flash_kernel(
    const float* __restrict__ hidden,        // fp32 (Q only)
    const unsigned short* __restrict__ Hpack,
    const int*   __restrict__ adj,           // [NN][NN] int32, read direct
    const float* __restrict__ W,
    const float* __restrict__ bvec,
    float*       __restrict__ Opart,         // [512][TN][DIM]
    float*       __restrict__ lpart)         // [512][TN]
{
    __shared__ __align__(16) unsigned short HH[2][TILE_USH];   // 71680 B
    __shared__ __align__(16) unsigned short Plc[TN * PST];     // 4608 B
    __shared__ float redsum[8][16];

    const int tid  = threadIdx.x;
    const int w    = tid >> 6;
    const int lane = tid & 63;
    const int g    = lane >> 4;
    const int l15  = lane & 15;
    const int blk  = blockIdx.x;
    const int nb   = blk >> 2;         // 0..127 row-group of 32
    const int qtr  = blk & 3;
    const int n0   = nb * TN;
    const int gt0  = qtr * NTILES;     // first global tile (of 64)
    const int rg   = w >> 2;           // 0/1: 16-row group
    const int ms   = w & 3;            // QK m-slice (16) / PV d-quarter (32)
    const int lofs = lane * 16;
    const float NEG = -9.0e15f;

    const float b0 = bvec[0], b1 = bvec[1], b2 = bvec[2], b3 = bvec[3];

    // ---- prologue: DMA tile 0 -> HH[0] ----
    {
        const char* src = (const char*)(Hpack + (size_t)gt0 * TILE_USH);
        char* dst = (char*)&HH[0][0];
        #pragma unroll
        for (int it = 0; it < 5; ++it) {
            int chunk = it * 8 + w;
            if (chunk < TILE_CHUNKS)
                dma16(src + chunk * 1024 + lofs, dst + chunk * 1024);
        }
    }
    // Q into HH[1] rows k*32+r (overlaps DMA)
    {
        int qr = tid >> 2;             // 0..127 = k*32 + r
        int r  = qr & 31;
        int d0 = (tid & 3) * 32;
        const float* hrow = hidden + (size_t)(n0 + r) * DIM + d0;
        const float* wrow = W + (qr >> 5) * DIM + d0;
        unsigned short* qdst = &HH[1][qr * LSTRIDE + d0];
        #pragma unroll
        for (int c = 0; c < 8; ++c) {
            float4 hv = *(const float4*)(hrow + 4 * c);
            float4 wv = *(const float4*)(wrow + 4 * c);
            ushort4 o;
            o.x = f2bf(hv.x * wv.x); o.y = f2bf(hv.y * wv.y);
            o.z = f2bf(hv.z * wv.z); o.w = f2bf(hv.w * wv.w);
            *(ushort4*)(qdst + 4 * c) = o;
        }
    }
    __syncthreads();   // drains tile-0 DMA (vmcnt) + Q LDS writes (lgkm)

    bf16x8 Af[4][4];
    #pragma unroll
    for (int k = 0; k < 4; ++k)
        #pragma unroll
        for (int ks = 0; ks < 4; ++ks)
            Af[k][ks] = *(const bf16x8*)&HH[1][(k * 32 + rg * 16 + l15) * LSTRIDE + ks * 32 + 8 * g];
    __syncthreads();   // Af reads drained before tile-1 DMA may write HH[1]

    float lrow[4] = {0.f, 0.f, 0.f, 0.f};
    f32x4 Oacc[2];
    Oacc[0] = (f32x4){0.f, 0.f, 0.f, 0.f};
    Oacc[1] = (f32x4){0.f, 0.f, 0.f, 0.f};

    // direct adj codes for tile 0 (4 coalesced int loads/lane)
    int avc[4], avn[4];
    #pragma unroll
    for (int t = 0; t < 4; ++t)
        avc[t] = adj[(size_t)(n0 + rg * 16 + 4 * g + t) * NN + gt0 * TM + ms * 16 + l15];

    for (int tile = 0; tile < NTILES; ++tile) {
        const int cur = tile & 1;
        const int nxt = cur ^ 1;

        // ---- issue next-tile DMA + adj prefetch; in flight all tile ----
        if (tile + 1 < NTILES) {
            const char* src = (const char*)(Hpack + (size_t)(gt0 + tile + 1) * TILE_USH);
            char* dst = (char*)&HH[nxt][0];
            #pragma unroll
            for (int it = 0; it < 5; ++it) {
                int chunk = it * 8 + w;
                if (chunk < TILE_CHUNKS)
                    dma16(src + chunk * 1024 + lofs, dst + chunk * 1024);
            }
            #pragma unroll
            for (int t = 0; t < 4; ++t)
                avn[t] = adj[(size_t)(n0 + rg * 16 + 4 * g + t) * NN + (gt0 + tile + 1) * TM + ms * 16 + l15];
        }

        // ---- QK: S[k] over m-slice [ms*16, +16) for rows rg*16..+16 ----
        f32x4 S[4];
        #pragma unroll
        for (int k = 0; k < 4; ++k) S[k] = (f32x4){0.f, 0.f, 0.f, 0.f};
        #pragma unroll
        for (int ks = 0; ks < 4; ++ks) {
            bf16x8 B = *(const bf16x8*)&HH[cur][(ms * 16 + l15) * LSTRIDE + ks * 32 + 8 * g];
            #pragma unroll
            for (int k = 0; k < 4; ++k)
                S[k] = __builtin_amdgcn_mfma_f32_16x16x32_bf16(Af[k][ks], B, S[k], 0, 0, 0);
        }

        // ---- select + leakyrelu + exp (no-max softmax; scores bounded) ----
        #pragma unroll
        for (int t = 0; t < 4; ++t) {
            int a = avc[t];
            float s = S[0][t] + b0;
            s = (a == 2) ? S[1][t] + b1 : s;
            s = (a == 3) ? S[2][t] + b2 : s;
            s = (a == 4) ? S[3][t] + b3 : s;
            float e = fmaxf(s, 0.2f * s);
            e = (a == 0) ? NEG : e;
            float p = __expf(e);           // exp(-9e15) -> exactly 0
            lrow[t] += p;
            Plc[(rg * 16 + 4 * g + t) * PST + ms * 16 + l15] = f2bf(p);
        }

        // ---- P-ready barrier: LDS-only drain; DMA stays in flight ----
        asm volatile("s_waitcnt lgkmcnt(0)\n\ts_barrier" ::: "memory");

        // ---- PV: rows rg*16..+16, d-quarter [ms*32, +32), K=64 ----
        #pragma unroll
        for (int c4 = 0; c4 < 2; ++c4) {
            bf16x8 Pa = *(const bf16x8*)&Plc[(rg * 16 + l15) * PST + c4 * 32 + 8 * g];
            #pragma unroll
            for (int dt = 0; dt < 2; ++dt) {
                bf16x8 Bv = *(const bf16x8*)&HH[cur][HROW_USH + (ms * 32 + dt * 16 + l15) * HCST + c4 * 32 + 8 * g];
                Oacc[dt] = __builtin_amdgcn_mfma_f32_16x16x32_bf16(Pa, Bv, Oacc[dt], 0, 0, 0);
            }
        }

        #pragma unroll
        for (int t = 0; t < 4; ++t) avc[t] = avn[t];
        __syncthreads();   // vmcnt(0) drain == "HH[nxt] staged"; buffer swap
    }

    // ---- epilogue ----
    #pragma unroll
    for (int t = 0; t < 4; ++t) {
        float v = lrow[t];
        v += __shfl_xor(v, 1); v += __shfl_xor(v, 2);
        v += __shfl_xor(v, 4); v += __shfl_xor(v, 8);
        if (l15 == 0) redsum[w][4 * g + t] = v;
    }
    __syncthreads();
    if (tid < 32) {
        int rgp = tid >> 4, rr = tid & 15;
        float s = redsum[rgp * 4 + 0][rr] + redsum[rgp * 4 + 1][rr]
                + redsum[rgp * 4 + 2][rr] + redsum[rgp * 4 + 3][rr];
        lpart[blk * 32 + tid] = s;
    }
    float* Ob = Opart + (size_t)blk * TN * DIM;
    #pragma unroll
    for (int dt = 0; dt < 2; ++dt)
        #pragma unroll
        for (int t = 0; t < 4; ++t)
            Ob[(rg * 16 + 4 * g + t) * DIM + ms * 32 + dt * 16 + l15] = Oacc[dt][t];
}

// ---- combine the four m-quarters ----
__global__ __launch_bounds__(256) void combine_kernel(
    const float* __restrict__ Opart, const float* __restrict__ lpart,
    float* __restrict__ out)
{
    int idx = blockIdx.x * 256 + threadIdx.x;
    int r = idx >> 7, d = idx & 127;
    int nb = r >> 5, rr = r & 31;
    float O = 0.f, l = 0.f;
    #pragma unroll
    for (int q = 0; q < NSPLIT; ++q) {
        O += Opart[(size_t)(nb * NSPLIT + q) * (TN * DIM) + rr * 128 + d];
        l += lpart[(nb * NSPLIT + q) * 32 + rr];
    }
    out[idx] = O / l;
}

extern "C" void kernel_launch(void* const* d_in, const int* in_sizes, int n_in,
                              void* d_out, int out_size, void* d_ws, size_t ws_size,
                              hipStream_t stream) {
    const float* hidden = (const float*)d_in[0];
    const int*   adj    = (const int*)d_in[1];
    const float* W      = (const float*)d_in[2];
    const float* b      = (const float*)d_in[3];
    float* out = (float*)d_out;

    char* ws = (char*)d_ws;
    unsigned short* Hpack = (unsigned short*)ws;                 // 64*35840 = 2.29 MB
    float* Opart = (float*)(ws + (4u << 20));                    // 512*32*128*4 = 8 MB
    float* lpart = (float*)(ws + (12u << 20));                   // 64 KB

    prep_pack_kernel<<<NN / TM, 256, 0, stream>>>(hidden, Hpack);
    gat_flash_kernel<<<512, 512, 0, stream>>>(hidden, Hpack, adj, W, b, Opart, lpart);
    combine_kernel<<<NN * DIM / 256, 256, 0, stream>>>(Opart, lpart, out);
}